// Round 18
// baseline (812.527 us; speedup 1.0000x reference)
//
#include <hip/hip_runtime.h>

// y = alpha*(x @ Q^T) + bias; alpha = mean|W|; Q = clip(round(W/alpha),-1,1)
// i8 path: Q ternary -> i8 exact; x per-row i8 (s_m = rowmax/127); i32 MFMA acc.
#define M_DIM 8192
#define N_DIM 16384
#define K_DIM 4096
#define NT 64  // K_DIM / 64

typedef unsigned short u16;
typedef unsigned int u32;
typedef signed char s8;
typedef __attribute__((ext_vector_type(4))) int i32x4;
typedef __attribute__((ext_vector_type(8))) signed char s8x8;
typedef __attribute__((ext_vector_type(4))) float f32x4;

#define MFMAI8(a, b, c) __builtin_amdgcn_mfma_i32_16x16x64_i8(a, b, c, 0, 0, 0)
#define SGB(mask, n) __builtin_amdgcn_sched_group_barrier((mask), (n), 0)

__device__ __forceinline__ void gload16(const void* g, void* l) {
  __builtin_amdgcn_global_load_lds((const __attribute__((address_space(1))) void*)g,
                                   (__attribute__((address_space(3))) void*)l, 16, 0, 0);
}

// --- fused: alpha partial-sums (blocks 0..4095) + per-row |x| max (4096..12287) ---
__global__ void reduce_rowmax(const float* __restrict__ w, const float* __restrict__ x,
                              double* __restrict__ partials, float* __restrict__ rowmax) {
  if (blockIdx.x < 4096) {
    const float4* w4 = (const float4*)w;
    size_t base = (size_t)blockIdx.x * 4096 + threadIdx.x;
    double s = 0.0;
#pragma unroll
    for (int i = 0; i < 16; ++i) {
      float4 v = w4[base + (size_t)i * 256];
      s += (double)fabsf(v.x); s += (double)fabsf(v.y);
      s += (double)fabsf(v.z); s += (double)fabsf(v.w);
    }
#pragma unroll
    for (int off = 32; off > 0; off >>= 1) s += __shfl_down(s, off, 64);
    __shared__ double red[4];
    int wv = threadIdx.x >> 6, lane = threadIdx.x & 63;
    if (lane == 0) red[wv] = s;
    __syncthreads();
    if (threadIdx.x == 0) partials[blockIdx.x] = (red[0] + red[1]) + (red[2] + red[3]);
  } else {
    const int row = blockIdx.x - 4096;
    const float4* x4 = (const float4*)(x + (size_t)row * K_DIM);
    float m = 0.f;
#pragma unroll
    for (int i = 0; i < 4; ++i) {
      float4 v = x4[threadIdx.x + i * 256];
      m = fmaxf(m, fmaxf(fmaxf(fabsf(v.x), fabsf(v.y)), fmaxf(fabsf(v.z), fabsf(v.w))));
    }
#pragma unroll
    for (int off = 32; off > 0; off >>= 1) m = fmaxf(m, __shfl_down(m, off, 64));
    __shared__ float redf[4];
    int wv = threadIdx.x >> 6, lane = threadIdx.x & 63;
    if (lane == 0) redf[wv] = m;
    __syncthreads();
    if (threadIdx.x == 0)
      rowmax[row] = fmaxf(fmaxf(redf[0], redf[1]), fmaxf(redf[2], redf[3]));
  }
}

__global__ void reduce_abs2(const double* __restrict__ partials,
                            double* __restrict__ alpha_d, float* __restrict__ alpha_f) {
  double s = 0.0;
  for (int i = threadIdx.x; i < 4096; i += 256) s += partials[i];
#pragma unroll
  for (int off = 32; off > 0; off >>= 1) s += __shfl_down(s, off, 64);
  __shared__ double red[4];
  int wv = threadIdx.x >> 6, lane = threadIdx.x & 63;
  if (lane == 0) red[wv] = s;
  __syncthreads();
  if (threadIdx.x == 0) {
    double total = (red[0] + red[1]) + (red[2] + red[3]);
    double a = total / (double)((long long)N_DIM * (long long)K_DIM);
    alpha_d[0] = a;
    alpha_f[0] = (float)a;
  }
}

// ---- fused prep: W -> ternary i8 Q; x -> per-row i8 (one dispatch) ----
__global__ void prep_wx(const float* __restrict__ w, const float* __restrict__ x,
                        const double* __restrict__ alpha_d, const float* __restrict__ rowmax,
                        s8* __restrict__ q, s8* __restrict__ xq) {
  const int b = blockIdx.x;
  if (b < 32768) {
    double inv = 1.0 / alpha_d[0];
    size_t i8i = (size_t)b * 256 + threadIdx.x;
    const float4* w4 = (const float4*)w;
    float4 v0 = w4[i8i * 2], v1 = w4[i8i * 2 + 1];
    float vv[8] = {v0.x, v0.y, v0.z, v0.w, v1.x, v1.y, v1.z, v1.w};
    s8x8 o;
#pragma unroll
    for (int j = 0; j < 8; ++j) {
      double r = rint((double)vv[j] * inv);  // RNE, matches np round
      s8 e = 0;
      if (r >= 1.0) e = 1;
      else if (r <= -1.0) e = -1;
      o[j] = e;
    }
    *((s8x8*)q + i8i) = o;
  } else {
    size_t i8i = (size_t)(b - 32768) * 256 + threadIdx.x;
    const int row = (b - 32768) >> 1;  // 2048 elems/block, 4096/row
    const float sv = 127.0f / rowmax[row];
    const float4* x4 = (const float4*)x;
    float4 v0 = x4[i8i * 2], v1 = x4[i8i * 2 + 1];
    float vv[8] = {v0.x, v0.y, v0.z, v0.w, v1.x, v1.y, v1.z, v1.w};
    s8x8 o;
#pragma unroll
    for (int j = 0; j < 8; ++j) o[j] = (s8)(int)rintf(vv[j] * sv);
    *((s8x8*)xq + i8i) = o;
  }
}

// --- 256x256-tile i8 GEMM: 16 waves (4 waves/SIMD TLP), 64x64 wave tiles ---
// 1024 threads = 16 waves (4M x 4N); per-wave 64x64 = acc[4][4] i32x4 (64 AGPR
// + ~50 VGPR <= 128 total -> all 16 waves resident = 4 waves/SIMD).
// Rationale: every 2-wave/SIMD config (R8-R17) serializes LDS wall + MFMA wall
// (2306cy/K-tile). 4 waves/SIMD gives the scheduler phase-diverse waves so one
// wave's MFMAs cover another's ds_read bursts (m114 mechanism). Block tile
// stays 256x256 (R14's staging-volume trap avoided). Walls: LDS 160KB=1250cy
// vs MFMA 1306cy -> overlap ceiling 1306cy (-43% GEMM).
// Keeps: ring-4 LDS (128 KiB), counted vmcnt (stage g+3, tile-end vmcnt(4) =
// tile g+1's 2 loads, issued 3 tiles earlier -- queue never drains),
// R13/R17-proven conflict-free chunk swizzle c=(q&3)^((row>>1)&3) (same byte
// geometry), SGB batches, no setprio, no intra-tile barriers, XCD swizzle.
__global__ __launch_bounds__(1024) void gemm_i8(
    const s8* __restrict__ A, const s8* __restrict__ Bq,
    const float* __restrict__ bias, const float* __restrict__ alpha_f,
    const float* __restrict__ rowmax, float* __restrict__ C) {
  __shared__ __align__(16) s8 Alds[4][256 * 64];  // 16 KiB per ring buffer
  __shared__ __align__(16) s8 Blds[4][256 * 64];

  const int t = threadIdx.x;
  const int wv = t >> 6, l = t & 63;
  const int wr = wv >> 2, wcn = wv & 3;  // 4M x 4N wave grid, 64x64 tiles
  const int lr = l & 15, lk = l >> 4;

  // XCD-bijective swizzle (2048 % 8 == 0) + 8(tm) x 64(tn) supertiles
  const int bid = blockIdx.x;
  const int wg = (bid & 7) * 256 + (bid >> 3);
  const int grp = wg >> 9, rem = wg & 511;
  const int tm = grp * 8 + (rem & 7);  // 0..31
  const int tn = rem >> 3;             // 0..63

  const s8* Ag = A + (size_t)tm * 256 * K_DIM;
  const s8* Bg = Bq + (size_t)tn * 256 * K_DIM;

  // Staging: thread t owns 16B chunk q = t of the [256][64B] tile:
  // row = q>>2, physical chunk pc = q&3 holds logical c = pc ^ ((row>>1)&3)
  // (R13-proven involution, 0 conflicts). LDS dest linear: wave-uniform
  // base wv*1024 + lane*16 (HW) = chunk q = wv*64 + l. One gload per matrix.
  const int srow = t >> 2, sc = (t & 3) ^ ((srow >> 1) & 3);
  const int so = srow * K_DIM + sc * 16;
  const int dof = wv * 1024;  // bytes

  // Frag read base (bytes): frag row = (wr*4+m)*16 + lr; (row>>1)&3 == (lr>>1)&3
  // (sub offsets are multiples of 8 rows) -> per-sub offset folds to immediate.
  const int fb = lr * 64 + ((lk ^ ((lr >> 1) & 3)) * 16);
#define LDA(b, m) (*(const i32x4*)(&Alds[b][(wr * 4 + (m)) * 1024 + fb]))
#define LDB(b, n) (*(const i32x4*)(&Blds[b][(wcn * 4 + (n)) * 1024 + fb]))

  i32x4 acc[4][4];
#pragma unroll
  for (int mi = 0; mi < 4; ++mi)
#pragma unroll
    for (int ni = 0; ni < 4; ++ni)
      acc[mi][ni] = (i32x4){0, 0, 0, 0};

  auto stageA = [&](int g) {
    if (g < NT) gload16(Ag + (size_t)g * 64 + so, &Alds[g & 3][dof]);
  };
  auto stageB = [&](int g) {
    if (g < NT) gload16(Bg + (size_t)g * 64 + so, &Blds[g & 3][dof]);
  };

#define MFMA4(m0, m1, n0, n1)                                                  \
  acc[m0][n0] = MFMAI8(aF[m0], bF[n0], acc[m0][n0]);                           \
  acc[m0][n1] = MFMAI8(aF[m0], bF[n1], acc[m0][n1]);                           \
  acc[m1][n0] = MFMAI8(aF[m1], bF[n0], acc[m1][n0]);                           \
  acc[m1][n1] = MFMAI8(aF[m1], bF[n1], acc[m1][n1])

  // one K-tile; b = kt&3 compile-time. 8 ds_reads + 16 MFMA per wave.
#define K_TILE(kt, b)                                                          \
  {                                                                            \
    i32x4 aF[4], bF[4];                                                        \
    /* pre: A0,A1,B0,B1 */                                                     \
    aF[0] = LDA(b, 0); aF[1] = LDA(b, 1);                                      \
    bF[0] = LDB(b, 0); bF[1] = LDB(b, 1);                                      \
    SGB(0x100, 4);                                                             \
    /* b0: R{A2,A3,B2}; stage A(kt+3); M{01 x 01} */                           \
    aF[2] = LDA(b, 2); aF[3] = LDA(b, 3);                                      \
    bF[2] = LDB(b, 2);                                                         \
    stageA((kt) + 3);                                                          \
    MFMA4(0, 1, 0, 1);                                                         \
    SGB(0x100, 3); SGB(0x20, 1); SGB(0x8, 4);                                  \
    /* b1: R{B3}; stage B(kt+3); M{23 x 01} */                                 \
    bF[3] = LDB(b, 3);                                                         \
    stageB((kt) + 3);                                                          \
    MFMA4(2, 3, 0, 1);                                                         \
    SGB(0x100, 1); SGB(0x20, 1); SGB(0x8, 4);                                  \
    /* b2: M{01 x 23} */                                                       \
    MFMA4(0, 1, 2, 3);                                                         \
    SGB(0x8, 4);                                                               \
    /* b3: M{23 x 23} */                                                       \
    MFMA4(2, 3, 2, 3);                                                         \
    SGB(0x8, 4);                                                               \
    /* tile end: counted wait -- only tile kt+1's 2 loads must be done */      \
    if ((kt) < NT - 3) {                                                       \
      asm volatile("s_waitcnt vmcnt(4)" ::: "memory");                         \
      __builtin_amdgcn_s_barrier();                                            \
    } else if ((kt) == NT - 3) {                                               \
      asm volatile("s_waitcnt vmcnt(2)" ::: "memory");                         \
      __builtin_amdgcn_s_barrier();                                            \
    } else if ((kt) == NT - 2) {                                               \
      asm volatile("s_waitcnt vmcnt(0)" ::: "memory");                         \
      __builtin_amdgcn_s_barrier();                                            \
    } /* last tile: no wait, epilogue follows */                               \
  }

  // prologue: stage tiles 0,1,2 (6 loads); wait for tile 0's 2 (vmcnt(4))
  stageA(0); stageB(0);
  stageA(1); stageB(1);
  stageA(2); stageB(2);
  asm volatile("s_waitcnt vmcnt(4)" ::: "memory");
  __builtin_amdgcn_s_barrier();

  for (int kt4 = 0; kt4 < NT; kt4 += 4) {
    K_TILE(kt4 + 0, 0);
    K_TILE(kt4 + 1, 1);
    K_TILE(kt4 + 2, 2);
    K_TILE(kt4 + 3, 3);
  }
#undef K_TILE
#undef MFMA4
#undef LDA
#undef LDB

  // epilogue: y = (alpha*rowmax/127) * acc + bias.  C/D: col=l&15, row=4*(l>>4)+j
  const float aw = alpha_f[0] * (1.0f / 127.0f);
#pragma unroll
  for (int ni = 0; ni < 4; ++ni) {
    const int col = tn * 256 + wcn * 64 + ni * 16 + lr;
    const float bs = bias[col];
#pragma unroll
    for (int mi = 0; mi < 4; ++mi) {
      const int rowbase = tm * 256 + wr * 64 + mi * 16 + lk * 4;
      const f32x4 rm = *(const f32x4*)&rowmax[rowbase];
      float* Cp = C + (size_t)rowbase * N_DIM + col;
#pragma unroll
      for (int j = 0; j < 4; ++j)
        Cp[(size_t)j * N_DIM] = aw * rm[j] * (float)acc[mi][ni][j] + bs;
    }
  }
}

extern "C" void kernel_launch(void* const* d_in, const int* in_sizes, int n_in,
                              void* d_out, int out_size, void* d_ws, size_t ws_size,
                              hipStream_t stream) {
  const float* x = (const float*)d_in[0];
  const float* w = (const float*)d_in[1];
  const float* bias = (const float*)d_in[2];
  float* out = (float*)d_out;

  char* ws = (char*)d_ws;
  double* alpha_d = (double*)ws;                    // [0,8)
  float* alpha_f = (float*)(ws + 8);                // [8,12)
  double* partials = (double*)(ws + 16);            // 32 KiB
  float* rowmax = (float*)(ws + 65536);             // 32 KiB (8192 f32)
  s8* xq = (s8*)(ws + 131072);                      // 32 MiB (M*K i8)
  s8* qb = (s8*)(ws + 131072 + 33554432ULL);        // 64 MiB (N*K i8)

  reduce_rowmax<<<12288, 256, 0, stream>>>(w, x, partials, rowmax);
  reduce_abs2<<<1, 256, 0, stream>>>(partials, alpha_d, alpha_f);
  prep_wx<<<49152, 256, 0, stream>>>(w, x, alpha_d, rowmax, qb, xq);
  gemm_i8<<<2048, 1024, 0, stream>>>(xq, qb, bias, alpha_f, rowmax, out);
}

// Round 20
// 789.168 us; speedup vs baseline: 1.0296x; 1.0296x over previous
//
#include <hip/hip_runtime.h>

// y = alpha*(x @ Q^T) + bias; alpha = mean|W|; Q = clip(round(W/alpha),-1,1)
// x:(2,4096,4096) f32, W:(16384,4096) f32, bias:(16384) f32, out f32.
// i8 path: Q is ternary -> i8 exact; x quantized per-row to i8 (s_m = rowmax/127);
// y = (alpha*s_m) * Sum(xq*Q) + bias with EXACT i32 MFMA accumulation.
#define M_DIM 8192
#define N_DIM 16384
#define K_DIM 4096
#define NT 64  // K_DIM / 64 (one mfma_i32_16x16x64_i8 per K-tile slice)

typedef unsigned short u16;
typedef unsigned int u32;
typedef signed char s8;
typedef __attribute__((ext_vector_type(4))) int i32x4;
typedef __attribute__((ext_vector_type(8))) signed char s8x8;
typedef __attribute__((ext_vector_type(4))) float f32x4;

#define MFMAI8(a, b, c) __builtin_amdgcn_mfma_i32_16x16x64_i8(a, b, c, 0, 0, 0)
#define SGB(mask, n) __builtin_amdgcn_sched_group_barrier((mask), (n), 0)

__device__ __forceinline__ void gload16(const void* g, void* l) {
  __builtin_amdgcn_global_load_lds((const __attribute__((address_space(1))) void*)g,
                                   (__attribute__((address_space(3))) void*)l, 16, 0, 0);
}

// ---------------- alpha = mean(|W|), f64 two-pass reduction ----------------
__global__ void reduce_abs1(const float* __restrict__ w, double* __restrict__ partials) {
  const float4* w4 = (const float4*)w;
  size_t base = (size_t)blockIdx.x * 4096 + threadIdx.x;
  double s = 0.0;
#pragma unroll
  for (int i = 0; i < 16; ++i) {
    float4 v = w4[base + (size_t)i * 256];
    s += (double)fabsf(v.x); s += (double)fabsf(v.y);
    s += (double)fabsf(v.z); s += (double)fabsf(v.w);
  }
#pragma unroll
  for (int off = 32; off > 0; off >>= 1) s += __shfl_down(s, off, 64);
  __shared__ double red[4];
  int wv = threadIdx.x >> 6, lane = threadIdx.x & 63;
  if (lane == 0) red[wv] = s;
  __syncthreads();
  if (threadIdx.x == 0) partials[blockIdx.x] = (red[0] + red[1]) + (red[2] + red[3]);
}

__global__ void reduce_abs2(const double* __restrict__ partials,
                            double* __restrict__ alpha_d, float* __restrict__ alpha_f) {
  double s = 0.0;
  for (int i = threadIdx.x; i < 4096; i += 256) s += partials[i];
#pragma unroll
  for (int off = 32; off > 0; off >>= 1) s += __shfl_down(s, off, 64);
  __shared__ double red[4];
  int wv = threadIdx.x >> 6, lane = threadIdx.x & 63;
  if (lane == 0) red[wv] = s;
  __syncthreads();
  if (threadIdx.x == 0) {
    double total = (red[0] + red[1]) + (red[2] + red[3]);
    double a = total / (double)((long long)N_DIM * (long long)K_DIM);
    alpha_d[0] = a;
    alpha_f[0] = (float)a;
  }
}

// ---- per-row x scales: sinv[m] = 127/rowmax, als[m] = alpha * rowmax/127 ----
__global__ void rowscale(const float* __restrict__ x, const float* __restrict__ alpha_f,
                         float* __restrict__ sinv, float* __restrict__ als) {
  const int row = blockIdx.x;
  const float4* x4 = (const float4*)(x + (size_t)row * K_DIM);
  float m = 0.f;
#pragma unroll
  for (int i = 0; i < 4; ++i) {
    float4 v = x4[threadIdx.x + i * 256];
    m = fmaxf(m, fmaxf(fmaxf(fabsf(v.x), fabsf(v.y)), fmaxf(fabsf(v.z), fabsf(v.w))));
  }
#pragma unroll
  for (int off = 32; off > 0; off >>= 1) m = fmaxf(m, __shfl_down(m, off, 64));
  __shared__ float red[4];
  int wv = threadIdx.x >> 6, lane = threadIdx.x & 63;
  if (lane == 0) red[wv] = m;
  __syncthreads();
  if (threadIdx.x == 0) {
    float mm = fmaxf(fmaxf(red[0], red[1]), fmaxf(red[2], red[3]));
    sinv[row] = 127.0f / mm;
    als[row] = alpha_f[0] * (mm / 127.0f);
  }
}

// ---- fused prep: W -> ternary i8 Q; x -> per-row i8 (one dispatch) ----
__global__ void prep_wx(const float* __restrict__ w, const float* __restrict__ x,
                        const double* __restrict__ alpha_d, const float* __restrict__ sinv,
                        s8* __restrict__ q, s8* __restrict__ xq) {
  const int b = blockIdx.x;
  if (b < 32768) {
    double inv = 1.0 / alpha_d[0];
    size_t i8i = (size_t)b * 256 + threadIdx.x;  // unit of 8 elems
    const float4* w4 = (const float4*)w;
    float4 v0 = w4[i8i * 2], v1 = w4[i8i * 2 + 1];
    float vv[8] = {v0.x, v0.y, v0.z, v0.w, v1.x, v1.y, v1.z, v1.w};
    s8x8 o;
#pragma unroll
    for (int j = 0; j < 8; ++j) {
      double r = rint((double)vv[j] * inv);  // RNE, matches np round
      s8 e = 0;
      if (r >= 1.0) e = 1;
      else if (r <= -1.0) e = -1;
      o[j] = e;
    }
    *((s8x8*)q + i8i) = o;
  } else {
    size_t i8i = (size_t)(b - 32768) * 256 + threadIdx.x;
    const int row = (b - 32768) >> 1;  // 2048 elems/block, 4096/row
    const float sv = sinv[row];
    const float4* x4 = (const float4*)x;
    float4 v0 = x4[i8i * 2], v1 = x4[i8i * 2 + 1];
    float vv[8] = {v0.x, v0.y, v0.z, v0.w, v1.x, v1.y, v1.z, v1.w};
    s8x8 o;
#pragma unroll
    for (int j = 0; j < 8; ++j) o[j] = (s8)(int)rintf(vv[j] * sv);  // in [-127,127]
    *((s8x8*)xq + i8i) = o;
  }
}

// --- 256x256-tile i8 GEMM: R13 skeleton byte-for-byte, i8 data, i32 acc ---
// (R17 exact revert -- proven stable, 577us GEMM / 789us total.)
// 512 threads = 8 waves (2M x 4N); per-wave 128x64 = acc[8][4] i32x4 (128 AGPR).
// LDS: 4 ring buffers x {A 256x64B, B 256x64B} = 128 KiB; conflict-free chunk
// swizzle c = (q&3)^((row>>1)&3) (R13-measured 0 conflicts, same byte geometry).
// K-tile = 64 i8: per wave 12 ds_reads + 32 mfma_i32_16x16x64_i8. T4 counted
// vmcnt: tile g stages g+3 into ring (g+3)&3; tile end waits vmcnt(8) (tile
// g+1's 4 loads, issued 3 tiles earlier) + s_barrier -- the barrier after the
// counted wait is REQUIRED for cross-wave DMA visibility (R19 lesson: a
// wave-local vmcnt alone races with other waves' in-flight stages).
// SGB batches; no setprio (R10); no intra-tile barriers (R6); XCD swizzle.
__global__ __launch_bounds__(512, 2) void gemm_i8(
    const s8* __restrict__ A, const s8* __restrict__ Bq,
    const float* __restrict__ bias, const float* __restrict__ als,
    float* __restrict__ C) {
  __shared__ __align__(16) s8 Alds[4][256 * 64];  // 16 KiB per ring buffer
  __shared__ __align__(16) s8 Blds[4][256 * 64];

  const int t = threadIdx.x;
  const int wv = t >> 6, l = t & 63;
  const int wr = wv >> 2, wc = wv & 3;  // 2M x 4N wave grid
  const int lr = l & 15, lk = l >> 4;

  // XCD-bijective swizzle (2048 % 8 == 0) + 8(tm) x 64(tn) supertiles
  const int bid = blockIdx.x;
  const int wg = (bid & 7) * 256 + (bid >> 3);
  const int grp = wg >> 9, rem = wg & 511;
  const int tm = grp * 8 + (rem & 7);  // 0..31
  const int tn = rem >> 3;             // 0..63

  const s8* Ag = A + (size_t)tm * 256 * K_DIM;
  const s8* Bg = Bq + (size_t)tn * 256 * K_DIM;

  // Staging: 16B chunk q in [0,1024) of a [256][64B] tile: row=q>>2, physical
  // chunk pc=q&3 holds logical c = pc ^ ((row>>1)&3) (involution; read applies
  // the same XOR). LDS dest linear (wave-uniform base + lane*16). Byte units.
  int so[2], dof[2];
#pragma unroll
  for (int s = 0; s < 2; ++s) {
    int qch = s * 512 + t;
    int row = qch >> 2, c = (qch & 3) ^ ((row >> 1) & 3);
    so[s] = row * K_DIM + c * 16;
    dof[s] = (s * 512 + wv * 64) * 16;
  }

  // Frag read base (bytes): row = sub*16 + lr, chunk lk^((lr>>1)&3);
  // per-sub offset sub*1024 folds to an immediate.
  const int fb = lr * 64 + ((lk ^ ((lr >> 1) & 3)) * 16);
#define LDA(b, m) (*(const i32x4*)(&Alds[b][wr * 8192 + (m) * 1024 + fb]))
#define LDB(b, n) (*(const i32x4*)(&Blds[b][wc * 4096 + (n) * 1024 + fb]))

  i32x4 acc[8][4];
#pragma unroll
  for (int mi = 0; mi < 8; ++mi)
#pragma unroll
    for (int ni = 0; ni < 4; ++ni)
      acc[mi][ni] = (i32x4){0, 0, 0, 0};

  // stage K-tile g into ring buffer g&3 (A: 2 gloads; B: 2 gloads per thread)
  auto stageA = [&](int g) {
    if (g < NT) {
      const s8* src = Ag + g * 64;
      gload16(src + so[0], &Alds[g & 3][dof[0]]);
      gload16(src + so[1], &Alds[g & 3][dof[1]]);
    }
  };
  auto stageB = [&](int g) {
    if (g < NT) {
      const s8* src = Bg + g * 64;
      gload16(src + so[0], &Blds[g & 3][dof[0]]);
      gload16(src + so[1], &Blds[g & 3][dof[1]]);
    }
  };

#define MFMA4(m0, m1, n0, n1)                                                  \
  acc[m0][n0] = MFMAI8(aF[m0], bF[n0], acc[m0][n0]);                           \
  acc[m0][n1] = MFMAI8(aF[m0], bF[n1], acc[m0][n1]);                           \
  acc[m1][n0] = MFMAI8(aF[m1], bF[n0], acc[m1][n0]);                           \
  acc[m1][n1] = MFMAI8(aF[m1], bF[n1], acc[m1][n1])

  // one K-tile; b = kt&3 compile-time at each expansion
#define K_TILE(kt, b)                                                          \
  {                                                                            \
    i32x4 aF[8], bF[4];                                                        \
    /* pre: A0,A1,B0,B1 */                                                     \
    aF[0] = LDA(b, 0); aF[1] = LDA(b, 1);                                      \
    bF[0] = LDB(b, 0); bF[1] = LDB(b, 1);                                      \
    SGB(0x100, 4);                                                             \
    /* b0: R{A2,A3,B2}; stage A(kt+3); M{01 x 01} */                           \
    aF[2] = LDA(b, 2); aF[3] = LDA(b, 3);                                      \
    bF[2] = LDB(b, 2);                                                         \
    stageA((kt) + 3);                                                          \
    MFMA4(0, 1, 0, 1);                                                         \
    SGB(0x100, 3); SGB(0x20, 2); SGB(0x8, 4);                                  \
    /* b1: R{A4,A5,B3}; stage B(kt+3); M{23 x 01} */                           \
    aF[4] = LDA(b, 4); aF[5] = LDA(b, 5);                                      \
    bF[3] = LDB(b, 3);                                                         \
    stageB((kt) + 3);                                                          \
    MFMA4(2, 3, 0, 1);                                                         \
    SGB(0x100, 3); SGB(0x20, 2); SGB(0x8, 4);                                  \
    /* b2: R{A6,A7}; M{01 x 23} */                                             \
    aF[6] = LDA(b, 6); aF[7] = LDA(b, 7);                                      \
    MFMA4(0, 1, 2, 3);                                                         \
    SGB(0x100, 2); SGB(0x8, 4);                                                \
    /* b3-b7: remaining MFMA quads */                                          \
    MFMA4(2, 3, 2, 3);                                                         \
    SGB(0x8, 4);                                                               \
    MFMA4(4, 5, 0, 1);                                                         \
    SGB(0x8, 4);                                                               \
    MFMA4(4, 5, 2, 3);                                                         \
    SGB(0x8, 4);                                                               \
    MFMA4(6, 7, 0, 1);                                                         \
    SGB(0x8, 4);                                                               \
    MFMA4(6, 7, 2, 3);                                                         \
    SGB(0x8, 4);                                                               \
    /* tile end: counted wait -- only tile kt+1's loads must be done */        \
    if ((kt) < NT - 3) {                                                       \
      asm volatile("s_waitcnt vmcnt(8)" ::: "memory");                         \
      __builtin_amdgcn_s_barrier();                                            \
    } else if ((kt) == NT - 3) {                                               \
      asm volatile("s_waitcnt vmcnt(4)" ::: "memory");                         \
      __builtin_amdgcn_s_barrier();                                            \
    } else if ((kt) == NT - 2) {                                               \
      asm volatile("s_waitcnt vmcnt(0)" ::: "memory");                         \
      __builtin_amdgcn_s_barrier();                                            \
    } /* last tile: no wait, epilogue follows */                               \
  }

  // prologue: stage tiles 0,1,2 (12 loads); wait for tile 0's 4 (vmcnt(8))
  stageA(0); stageB(0);
  stageA(1); stageB(1);
  stageA(2); stageB(2);
  asm volatile("s_waitcnt vmcnt(8)" ::: "memory");
  __builtin_amdgcn_s_barrier();

  for (int kt4 = 0; kt4 < NT; kt4 += 4) {
    K_TILE(kt4 + 0, 0);
    K_TILE(kt4 + 1, 1);
    K_TILE(kt4 + 2, 2);
    K_TILE(kt4 + 3, 3);
  }
#undef K_TILE
#undef MFMA4
#undef LDA
#undef LDB

  // epilogue: y = als[row] * acc + bias.  C/D: col=l&15, row=4*(l>>4)+j
  // (16x16 C/D layout is dtype-independent on gfx950 -- m121/m124 i8-verified)
#pragma unroll
  for (int ni = 0; ni < 4; ++ni) {
    const int col = tn * 256 + wc * 64 + ni * 16 + lr;
    const float bs = bias[col];
#pragma unroll
    for (int mi = 0; mi < 8; ++mi) {
      const int rowbase = tm * 256 + wr * 128 + mi * 16 + lk * 4;
      const f32x4 av = *(const f32x4*)&als[rowbase];
      float* Cp = C + (size_t)rowbase * N_DIM + col;
#pragma unroll
      for (int j = 0; j < 4; ++j)
        Cp[(size_t)j * N_DIM] = av[j] * (float)acc[mi][ni][j] + bs;
    }
  }
}

extern "C" void kernel_launch(void* const* d_in, const int* in_sizes, int n_in,
                              void* d_out, int out_size, void* d_ws, size_t ws_size,
                              hipStream_t stream) {
  const float* x = (const float*)d_in[0];
  const float* w = (const float*)d_in[1];
  const float* bias = (const float*)d_in[2];
  float* out = (float*)d_out;

  char* ws = (char*)d_ws;
  double* alpha_d = (double*)ws;                    // [0,8)
  float* alpha_f = (float*)(ws + 8);                // [8,12)
  double* partials = (double*)(ws + 16);            // 32 KiB
  float* sinv = (float*)(ws + 65536);               // 32 KiB (8192 f32)
  float* als = (float*)(ws + 98304);                // 32 KiB
  s8* xq = (s8*)(ws + 131072);                      // 32 MiB (M*K i8)
  s8* qb = (s8*)(ws + 131072 + 33554432ULL);        // 64 MiB (N*K i8)
  // total ~100.8 MiB

  reduce_abs1<<<4096, 256, 0, stream>>>(w, partials);
  reduce_abs2<<<1, 256, 0, stream>>>(partials, alpha_d, alpha_f);
  rowscale<<<8192, 256, 0, stream>>>(x, alpha_f, sinv, als);
  prep_wx<<<49152, 256, 0, stream>>>(w, x, alpha_d, sinv, qb, xq);
  gemm_i8<<<2048, 512, 0, stream>>>(xq, qb, bias, als, out);
}